// Round 10
// baseline (32.446 us; speedup 1.0000x reference)
//
#include <hip/hip_runtime.h>
#include <math.h>

#define BS 16
#define NQ 100
#define NPTS 25
#define VOC 96
#define NC 97              // VOC+1 classes incl. padding
#define MAXLEN 25
#define NGT 32
#define EDIM 300
#define NCOL 512           // BS*NGT
#define NDIM 50            // NPTS*2
#define RPB 10             // rows per assemble block (divides 100)

// ---------------- workspace layout (floats) ----------------
#define WS_GRAM 0                       // 97*96 = 9312 (row 96 = zeros)
#define WS_LOGP (WS_GRAM + NC * VOC)    // 1600*96
#define WS_CC   (WS_LOGP + 1600 * VOC)  // 1600
#define WS_TGTT (WS_CC + 1600)          // 50*512

#define GRAM_BLKS VOC              // 96
#define PRED_BLKS 1600
#define TR_BLKS 200                // 200*128 = 25600
#define K1_BLKS (GRAM_BLKS + PRED_BLKS + TR_BLKS)

// ---- K1 (frozen from R8/R9 — register-resident pred softmax): gram | pred | transpose
__global__ __launch_bounds__(128) void k1_kernel(
        const float* __restrict__ logits1,   // (1600,25,1)
        const float* __restrict__ tlogits,   // (1600,25,97)
        const float* __restrict__ cen,       // (96,300)
        const float* __restrict__ tgt_pts,   // (512,50)
        float* __restrict__ gram, float* __restrict__ logp,
        float* __restrict__ cost_class, float* __restrict__ tgtT) {
    __shared__ float smem[448];              // gram: row[0..300)+red[320..448); pred: pA[2][97]
    int blk = blockIdx.x, tid = threadIdx.x;
    int wave = tid >> 6, lane = tid & 63;

    if (blk < GRAM_BLKS) {
        // ---- gram row v = blk: softmax_c( dot(cen[v],cen[c]) / sqrt(300) ), no max pass
        float* row = smem;                   // 300
        float* red = smem + 320;             // 128
        for (int k = tid; k < EDIM; k += 128) row[k] = cen[blk * EDIM + k];
        if (blk == 0 && tid < VOC) gram[VOC * VOC + tid] = 0.f;   // zero pad row
        __syncthreads();
        float e = 0.f;
        if (tid < VOC) {
            float a0 = 0.f, a1 = 0.f;
            const float* c = cen + (size_t)tid * EDIM;
            for (int k = 0; k < EDIM; k += 2) { a0 += row[k] * c[k]; a1 += row[k + 1] * c[k + 1]; }
            e = __expf((a0 + a1) * 0.05773502691896258f);
        }
        red[tid] = e;
        __syncthreads();
        for (int s = 64; s; s >>= 1) { if (tid < s) red[tid] += red[tid + s]; __syncthreads(); }
        if (tid < VOC) gram[blk * VOC + tid] = e / red[0];
    } else if (blk < GRAM_BLKS + PRED_BLKS) {
        // ---- pred unit: register-resident softmax, interleaved cross-lane reductions
        int u = blk - GRAM_BLKS;
        const float* base = tlogits + (size_t)u * NPTS * NC;
        float e0[13], e1[13], s[13], vm[13];
        int p0 = wave * 13;                  // wave0: 13 pts, wave1: 12 pts
#pragma unroll
        for (int i = 0; i < 13; ++i) {
            int p = p0 + i;
            bool ok = p < NPTS;
            vm[i] = ok ? 1.f : 0.f;
            int pe = ok ? p : 0;
            float x0 = base[pe * NC + lane];
            float x1 = (lane < 33) ? base[pe * NC + 64 + lane] : 0.f;
            e0[i] = __expf(x0);
            e1[i] = (lane < 33) ? __expf(x1) : 0.f;
            s[i] = e0[i] + e1[i];
        }
        // 13 independent 6-step xor-reduce chains, interleaved -> pipelined
#pragma unroll
        for (int st = 32; st; st >>= 1) {
#pragma unroll
            for (int i = 0; i < 13; ++i) s[i] += __shfl_xor(s[i], st);
        }
        float part0 = 0.f, part1 = 0.f;
#pragma unroll
        for (int i = 0; i < 13; ++i) {
            float rinv = vm[i] / s[i];       // invalid slot -> 0 (s finite >0)
            part0 += e0[i] * rinv;
            part1 += e1[i] * rinv;
        }
        float* pA = smem;                    // [2][97]
        pA[wave * 97 + lane] = part0;
        if (lane < 33) pA[wave * 97 + 64 + lane] = part1;
        __syncthreads();
        if (tid < VOC) {
            float tot = (pA[tid] + pA[97 + tid]) * 0.04f;
            logp[(size_t)u * VOC + tid] = __logf(fmaxf(tot, 1e-6f));
        }
        if (wave == 1) {                     // wave1 has the spare slot
            float sig = 0.f;
            if (lane < NPTS) { float x = logits1[u * NPTS + lane]; sig = 1.f / (1.f + __expf(-x)); }
#pragma unroll
            for (int o = 32; o; o >>= 1) sig += __shfl_xor(sig, o);
            if (lane == 0) {
                float prob = sig * 0.04f;
                float negc = 0.75f * prob * prob * (-__logf(1.f - prob + 1e-8f));
                float posc = 0.25f * (1.f - prob) * (1.f - prob) * (-__logf(prob + 1e-8f));
                cost_class[u] = posc - negc;
            }
        }
    } else {
        // ---- transpose tgt points (512,50) -> (50,512)
        int g = (blk - GRAM_BLKS - PRED_BLKS) * 128 + tid;   // < 25600 exactly
        int k = g / NCOL;
        int j = g - k * NCOL;
        tgtT[g] = tgt_pts[(size_t)j * NDIM + k];
    }
}

// ================= K2: fused stats + assemble; gram table staged in LDS =================
// 160 blocks x 512 thr; block owns rows r0 = blk*10 .. r0+9, all in image b = blk/10.
__global__ __launch_bounds__(512) void k2_kernel(
        const float* __restrict__ pred_pts,  // (1600,50)
        const float* __restrict__ tgtT,      // (50,512)
        const float* __restrict__ gram,      // (97,96), row 96 zeros
        const int*   __restrict__ texts,     // (512,25)
        const float* __restrict__ logp,      // (1600,96)
        const float* __restrict__ cc,        // (1600,)
        float* __restrict__ out) {           // (1600,512)
    __shared__ float s_gram[NC * VOC];       // 9312 floats = 37.2 KB (incl. zero row)
    __shared__ float s_stat[NGT][NC];        // ts[0..95], [96]=neg_ent (stride 97)
    __shared__ float s_lp[RPB][VOC];
    __shared__ float s_pp[RPB][NDIM];
    __shared__ float s_cc[RPB];
    __shared__ float s_ct[RPB][NGT];
    __shared__ int   s_tex[NGT * MAXLEN];    // 800

    int blk = blockIdx.x, tid = threadIdx.x;
    int wave = tid >> 6, lane = tid & 63;
    int r0 = blk * RPB;
    int b = blk / (NQ / RPB);                // = r0/100

    // ---- staging (all coalesced, independent loads; one barrier)
    for (int i = tid; i < NC * VOC; i += 512) s_gram[i] = gram[i];
    for (int i = tid; i < NGT * MAXLEN; i += 512) s_tex[i] = texts[b * NGT * MAXLEN + i];
    for (int i = tid; i < RPB * VOC; i += 512) s_lp[i / VOC][i % VOC] = logp[(size_t)r0 * VOC + i];
    if (tid < RPB * NDIM) s_pp[tid / NDIM][tid % NDIM] = pred_pts[(size_t)r0 * NDIM + tid];
    if (tid < RPB) s_cc[tid] = cc[r0 + tid];
    __syncthreads();

    // ---- stats: 8 waves x 4 g's; gathers now LDS (wave-uniform row, lane stride-1)
    for (int j = 0; j < NGT / 8; ++j) {
        int g = wave * 4 + j;
        const int* tx = s_tex + g * MAXLEN;
        int vv[MAXLEN];
#pragma unroll
        for (int l = 0; l < MAXLEN; ++l) vv[l] = tx[l];   // 25 independent LDS reads
        int len = 0;
#pragma unroll
        for (int l = 0; l < MAXLEN; ++l) len += (vv[l] != VOC);
        float a0 = 0.f, a1 = 0.f;
#pragma unroll
        for (int l0 = 0; l0 < MAXLEN; l0 += 5) {
            float b0[5], b1[5];
#pragma unroll
            for (int q = 0; q < 5; ++q) {                 // 10 LDS reads in flight
                const float* gr = s_gram + vv[l0 + q] * VOC;  // row 96 = zeros
                b0[q] = gr[lane];
                b1[q] = (lane < 32) ? gr[64 + lane] : 0.f;
            }
#pragma unroll
            for (int q = 0; q < 5; ++q) { a0 += b0[q]; a1 += b1[q]; }
        }
        float dinv = 1.f / (float)(len > 0 ? len : 1);
        float t0 = fmaxf(a0 * dinv, 1e-6f);
        float t1 = (lane < 32) ? fmaxf(a1 * dinv, 1e-6f) : 0.f;
        float s = t0 + t1;
#pragma unroll
        for (int o = 32; o; o >>= 1) s += __shfl_xor(s, o);
        float inv = 1.f / s;
        float ts0 = t0 * inv, ts1 = t1 * inv;
        float c0 = ts0 * __logf(ts0);
        float c1 = (lane < 32) ? ts1 * __logf(ts1) : 0.f;
        float ent = c0 + c1;
#pragma unroll
        for (int o = 32; o; o >>= 1) ent += __shfl_xor(ent, o);
        s_stat[g][lane] = len ? ts0 : 0.f;
        if (lane < 32) s_stat[g][64 + lane] = len ? ts1 : 0.f;
        if (lane == 0) s_stat[g][VOC] = len ? ent : 100.f;
    }
    __syncthreads();

    // ---- KL: 320 threads, one (row,g) dot each
    if (tid < RPB * NGT) {
        int row = tid >> 5, g = tid & 31;
        const float* L = s_lp[row];              // broadcast
        const float* S = s_stat[g];              // stride 97 -> conflict-free
        float d0 = 0.f, d1 = 0.f, d2 = 0.f, d3 = 0.f;
#pragma unroll
        for (int c = 0; c < VOC; c += 4) {
            d0 += L[c]     * S[c];
            d1 += L[c + 1] * S[c + 1];
            d2 += L[c + 2] * S[c + 2];
            d3 += L[c + 3] * S[c + 3];
        }
        s_ct[row][g] = fmaxf(S[VOC] - (d0 + d1 + d2 + d3), 0.f);
    }
    __syncthreads();

    // ---- joint L1 sweep: 1 col/thread, all 10 rows per tgtT read
    float acc[RPB];
#pragma unroll
    for (int r = 0; r < RPB; ++r) acc[r] = 0.f;
#pragma unroll 5
    for (int k = 0; k < NDIM; ++k) {
        float tv = tgtT[(k << 9) + tid];
#pragma unroll
        for (int r = 0; r < RPB; ++r) acc[r] += fabsf(s_pp[r][k] - tv);
    }

    int gb = tid >> 5, g = tid & 31;
    float text = (gb == b) ? 1.f : 0.f;
#pragma unroll
    for (int r = 0; r < RPB; ++r) {
        out[(size_t)(r0 + r) * NCOL + tid] = s_cc[r] + acc[r] + text * s_ct[r][g];
    }
}

extern "C" void kernel_launch(void* const* d_in, const int* in_sizes, int n_in,
                              void* d_out, int out_size, void* d_ws, size_t ws_size,
                              hipStream_t stream) {
    const float* pred_logits      = (const float*)d_in[0];
    const float* pred_ctrl_points = (const float*)d_in[1];
    const float* pred_text_logits = (const float*)d_in[2];
    const float* tgt_ctrl_points  = (const float*)d_in[3];
    const int*   target_texts     = (const int*)d_in[4];
    const float* centroids        = (const float*)d_in[5];
    float* out = (float*)d_out;
    float* ws  = (float*)d_ws;

    float* gram = ws + WS_GRAM;
    float* logp = ws + WS_LOGP;
    float* cc   = ws + WS_CC;
    float* tgtT = ws + WS_TGTT;

    k1_kernel<<<K1_BLKS, 128, 0, stream>>>(pred_logits, pred_text_logits, centroids,
                                           tgt_ctrl_points, gram, logp, cc, tgtT);
    k2_kernel<<<(BS * NQ) / RPB, 512, 0, stream>>>(pred_ctrl_points, tgtT, gram,
                                                   target_texts, logp, cc, out);
}

// Round 11
// 28.407 us; speedup vs baseline: 1.1422x; 1.1422x over previous
//
#include <hip/hip_runtime.h>
#include <math.h>

#define BS 16
#define NQ 100
#define NPTS 25
#define VOC 96
#define NC 97              // VOC+1 classes incl. padding
#define MAXLEN 25
#define NGT 32
#define EDIM 300
#define NCOL 512           // BS*NGT
#define NDIM 50            // NPTS*2

// ---------------- workspace layout (floats) ----------------
#define WS_GRAM 0                       // 97*96 = 9312 (row 96 = zeros)
#define WS_LOGP (WS_GRAM + NC * VOC)    // 1600*96
#define WS_CC   (WS_LOGP + 1600 * VOC)  // 1600
#define WS_TGTT (WS_CC + 1600)          // 50*512
#define WS_STAT (WS_TGTT + NDIM * NCOL) // 512*97: [pair][0..95]=ts, [96]=neg_ent

#define GRAM_BLKS VOC              // 96
#define PRED_BLKS 1600
#define TR_BLKS 200                // 200*128 = 25600
#define K1_BLKS (GRAM_BLKS + PRED_BLKS + TR_BLKS)

// ---- K1 (frozen from R8/R9 — register-resident pred softmax): gram | pred | transpose
__global__ __launch_bounds__(128) void k1_kernel(
        const float* __restrict__ logits1,   // (1600,25,1)
        const float* __restrict__ tlogits,   // (1600,25,97)
        const float* __restrict__ cen,       // (96,300)
        const float* __restrict__ tgt_pts,   // (512,50)
        float* __restrict__ gram, float* __restrict__ logp,
        float* __restrict__ cost_class, float* __restrict__ tgtT) {
    __shared__ float smem[448];              // gram: row[0..300)+red[320..448); pred: pA[2][97]
    int blk = blockIdx.x, tid = threadIdx.x;
    int wave = tid >> 6, lane = tid & 63;

    if (blk < GRAM_BLKS) {
        float* row = smem;                   // 300
        float* red = smem + 320;             // 128
        for (int k = tid; k < EDIM; k += 128) row[k] = cen[blk * EDIM + k];
        if (blk == 0 && tid < VOC) gram[VOC * VOC + tid] = 0.f;   // zero pad row
        __syncthreads();
        float e = 0.f;
        if (tid < VOC) {
            float a0 = 0.f, a1 = 0.f;
            const float* c = cen + (size_t)tid * EDIM;
            for (int k = 0; k < EDIM; k += 2) { a0 += row[k] * c[k]; a1 += row[k + 1] * c[k + 1]; }
            e = __expf((a0 + a1) * 0.05773502691896258f);
        }
        red[tid] = e;
        __syncthreads();
        for (int s = 64; s; s >>= 1) { if (tid < s) red[tid] += red[tid + s]; __syncthreads(); }
        if (tid < VOC) gram[blk * VOC + tid] = e / red[0];
    } else if (blk < GRAM_BLKS + PRED_BLKS) {
        int u = blk - GRAM_BLKS;
        const float* base = tlogits + (size_t)u * NPTS * NC;
        float e0[13], e1[13], s[13], vm[13];
        int p0 = wave * 13;                  // wave0: 13 pts, wave1: 12 pts
#pragma unroll
        for (int i = 0; i < 13; ++i) {
            int p = p0 + i;
            bool ok = p < NPTS;
            vm[i] = ok ? 1.f : 0.f;
            int pe = ok ? p : 0;
            float x0 = base[pe * NC + lane];
            float x1 = (lane < 33) ? base[pe * NC + 64 + lane] : 0.f;
            e0[i] = __expf(x0);
            e1[i] = (lane < 33) ? __expf(x1) : 0.f;
            s[i] = e0[i] + e1[i];
        }
#pragma unroll
        for (int st = 32; st; st >>= 1) {
#pragma unroll
            for (int i = 0; i < 13; ++i) s[i] += __shfl_xor(s[i], st);
        }
        float part0 = 0.f, part1 = 0.f;
#pragma unroll
        for (int i = 0; i < 13; ++i) {
            float rinv = vm[i] / s[i];
            part0 += e0[i] * rinv;
            part1 += e1[i] * rinv;
        }
        float* pA = smem;                    // [2][97]
        pA[wave * 97 + lane] = part0;
        if (lane < 33) pA[wave * 97 + 64 + lane] = part1;
        __syncthreads();
        if (tid < VOC) {
            float tot = (pA[tid] + pA[97 + tid]) * 0.04f;
            logp[(size_t)u * VOC + tid] = __logf(fmaxf(tot, 1e-6f));
        }
        if (wave == 1) {
            float sig = 0.f;
            if (lane < NPTS) { float x = logits1[u * NPTS + lane]; sig = 1.f / (1.f + __expf(-x)); }
#pragma unroll
            for (int o = 32; o; o >>= 1) sig += __shfl_xor(sig, o);
            if (lane == 0) {
                float prob = sig * 0.04f;
                float negc = 0.75f * prob * prob * (-__logf(1.f - prob + 1e-8f));
                float posc = 0.25f * (1.f - prob) * (1.f - prob) * (-__logf(prob + 1e-8f));
                cost_class[u] = posc - negc;
            }
        }
    } else {
        int g = (blk - GRAM_BLKS - PRED_BLKS) * 128 + tid;   // < 25600 exactly
        int k = g / NCOL;
        int j = g - k * NCOL;
        tgtT[g] = tgt_pts[(size_t)j * NDIM + k];
    }
}

// ================= K2a: tgt-stats, 128 blocks x 256, 1 pair per wave =================
__global__ __launch_bounds__(256) void stats_kernel(
        const int*   __restrict__ texts,     // (512,25)
        const float* __restrict__ gram,      // (97,96), row 96 zeros
        float* __restrict__ stat) {          // (512,97)
    __shared__ int s_tex[4 * MAXLEN];
    int blk = blockIdx.x, tid = threadIdx.x;
    int wave = tid >> 6, lane = tid & 63;
    if (tid < 4 * MAXLEN) s_tex[tid] = texts[blk * 4 * MAXLEN + tid];
    __syncthreads();

    int vv[MAXLEN];
#pragma unroll
    for (int l = 0; l < MAXLEN; ++l) vv[l] = s_tex[wave * MAXLEN + l];
    int len = 0;
#pragma unroll
    for (int l = 0; l < MAXLEN; ++l) len += (vv[l] != VOC);
    float a0 = 0.f, a1 = 0.f;
#pragma unroll
    for (int l0 = 0; l0 < MAXLEN; l0 += 5) {
        float b0[5], b1[5];
#pragma unroll
        for (int q = 0; q < 5; ++q) {                 // 10 loads in flight
            const float* gr = gram + vv[l0 + q] * VOC;   // row 96 = zeros
            b0[q] = gr[lane];
            b1[q] = (lane < 32) ? gr[64 + lane] : 0.f;
        }
#pragma unroll
        for (int q = 0; q < 5; ++q) { a0 += b0[q]; a1 += b1[q]; }
    }
    float dinv = 1.f / (float)(len > 0 ? len : 1);
    float t0 = fmaxf(a0 * dinv, 1e-6f);
    float t1 = (lane < 32) ? fmaxf(a1 * dinv, 1e-6f) : 0.f;
    float s = t0 + t1;
#pragma unroll
    for (int o = 32; o; o >>= 1) s += __shfl_xor(s, o);
    float inv = 1.f / s;
    float ts0 = t0 * inv, ts1 = t1 * inv;
    float c0 = ts0 * __logf(ts0);
    float c1 = (lane < 32) ? ts1 * __logf(ts1) : 0.f;
    float ent = c0 + c1;
#pragma unroll
    for (int o = 32; o; o >>= 1) ent += __shfl_xor(ent, o);
    float* dst = stat + (size_t)(blk * 4 + wave) * NC;
    dst[lane] = len ? ts0 : 0.f;
    if (lane < 32) dst[64 + lane] = len ? ts1 : 0.f;
    if (lane == 0) dst[VOC] = len ? ent : 100.f;
}

// ================= K2b: pure assemble, 800 blocks x 256, 2 rows/block =================
__global__ __launch_bounds__(256) void asm_kernel(
        const float* __restrict__ pred_pts,  // (1600,50)
        const float* __restrict__ tgtT,      // (50,512)
        const float* __restrict__ logp,      // (1600,96)
        const float* __restrict__ cc,        // (1600,)
        const float* __restrict__ stat,      // (512,97)
        float* __restrict__ out) {           // (1600,512)
    __shared__ float s_stat[NGT * NC];       // 3104 (stride 97)
    __shared__ float s_lp[2][VOC];
    __shared__ float s_pp[2][NDIM];
    __shared__ float s_ct[2][NGT];
    __shared__ float spart[256];
    __shared__ float s_cc[2];

    int blk = blockIdx.x, tid = threadIdx.x;
    int r0 = blk * 2;
    int b = blk / 50;                        // = r0/100 (rows 2k,2k+1 share image)

    // ---- stage (all coalesced / tiny)
    for (int i = tid; i < NGT * NC; i += 256) s_stat[i] = stat[(size_t)b * NGT * NC + i];
    if (tid < 2 * VOC) { int r = tid >= VOC, c = tid - r * VOC; s_lp[r][c] = logp[(size_t)(r0 + r) * VOC + c]; }
    if (tid < 2 * NDIM) { int r = tid >= NDIM, k = tid - r * NDIM; s_pp[r][k] = pred_pts[(size_t)(r0 + r) * NDIM + k]; }
    if (tid < 2) s_cc[tid] = cc[r0 + tid];
    __syncthreads();

    // ---- KL partials: 256 thr = 64 (row,g) pairs x 4 sub-chunks of 24
    {
        int pair = tid >> 2, sub = tid & 3;
        int row = pair >> 5, g = pair & 31;
        const float* L = s_lp[row] + sub * 24;       // broadcast within 16-lane groups
        const float* S = s_stat + g * NC + sub * 24; // ≤2-way bank alias (free)
        float d0 = 0.f, d1 = 0.f;
#pragma unroll
        for (int j = 0; j < 24; j += 2) { d0 += L[j] * S[j]; d1 += L[j + 1] * S[j + 1]; }
        spart[tid] = d0 + d1;
    }
    __syncthreads();
    if (tid < 2 * NGT) {
        int row = tid >> 5, g = tid & 31;
        float s = spart[tid * 4] + spart[tid * 4 + 1] + spart[tid * 4 + 2] + spart[tid * 4 + 3];
        s_ct[row][g] = fmaxf(s_stat[g * NC + VOC] - s, 0.f);
    }

    // ---- L1 sweep: 2 rows x 2 col-halves, deep unroll for load pipelining
    float a00 = 0.f, a01 = 0.f, a10 = 0.f, a11 = 0.f;
#pragma unroll 10
    for (int k = 0; k < NDIM; ++k) {
        float tv0 = tgtT[(k << 9) + tid];
        float tv1 = tgtT[(k << 9) + 256 + tid];
        float p0 = s_pp[0][k], p1 = s_pp[1][k];
        a00 += fabsf(p0 - tv0);
        a01 += fabsf(p0 - tv1);
        a10 += fabsf(p1 - tv0);
        a11 += fabsf(p1 - tv1);
    }
    __syncthreads();                         // s_ct visible

    int gb = tid >> 5, g = tid & 31;
    float c0v = s_cc[0], c1v = s_cc[1];
    float m0 = (gb == b) ? 1.f : 0.f;        // col tid is image gb
    float m1 = (8 + gb == b) ? 1.f : 0.f;    // col tid+256 is image 8+gb
    out[(size_t)r0 * NCOL + tid]             = c0v + a00 + m0 * s_ct[0][g];
    out[(size_t)r0 * NCOL + 256 + tid]       = c0v + a01 + m1 * s_ct[0][g];
    out[(size_t)(r0 + 1) * NCOL + tid]       = c1v + a10 + m0 * s_ct[1][g];
    out[(size_t)(r0 + 1) * NCOL + 256 + tid] = c1v + a11 + m1 * s_ct[1][g];
}

extern "C" void kernel_launch(void* const* d_in, const int* in_sizes, int n_in,
                              void* d_out, int out_size, void* d_ws, size_t ws_size,
                              hipStream_t stream) {
    const float* pred_logits      = (const float*)d_in[0];
    const float* pred_ctrl_points = (const float*)d_in[1];
    const float* pred_text_logits = (const float*)d_in[2];
    const float* tgt_ctrl_points  = (const float*)d_in[3];
    const int*   target_texts     = (const int*)d_in[4];
    const float* centroids        = (const float*)d_in[5];
    float* out = (float*)d_out;
    float* ws  = (float*)d_ws;

    float* gram = ws + WS_GRAM;
    float* logp = ws + WS_LOGP;
    float* cc   = ws + WS_CC;
    float* tgtT = ws + WS_TGTT;
    float* stat = ws + WS_STAT;

    k1_kernel<<<K1_BLKS, 128, 0, stream>>>(pred_logits, pred_text_logits, centroids,
                                           tgt_ctrl_points, gram, logp, cc, tgtT);
    stats_kernel<<<128, 256, 0, stream>>>(target_texts, gram, stat);
    asm_kernel<<<800, 256, 0, stream>>>(pred_ctrl_points, tgtT, logp, cc, stat, out);
}

// Round 12
// 25.143 us; speedup vs baseline: 1.2904x; 1.1298x over previous
//
#include <hip/hip_runtime.h>
#include <math.h>

#define BS 16
#define NQ 100
#define NPTS 25
#define VOC 96
#define NC 97              // VOC+1 classes incl. padding
#define MAXLEN 25
#define NGT 32
#define EDIM 300
#define NCOL 512           // BS*NGT
#define NDIM 50            // NPTS*2

// ---------------- workspace layout (floats) ----------------
#define WS_GRAM 0                       // 97*96 = 9312 (row 96 = zeros)
#define WS_LOGP (WS_GRAM + NC * VOC)    // 1600*96
#define WS_CC   (WS_LOGP + 1600 * VOC)  // 1600
#define WS_TGTT (WS_CC + 1600)          // 50*512
#define WS_STAT (WS_TGTT + NDIM * NCOL) // 512*97: [pair][0..95]=ts, [96]=neg_ent

#define GRAM_BLKS VOC              // 96
#define PRED_BLKS 1600
#define TR_BLKS 200                // 200*128 = 25600
#define K1_BLKS (GRAM_BLKS + PRED_BLKS + TR_BLKS)

// ---- K1 (frozen from R8/R9 — register-resident pred softmax): gram | pred | transpose
__global__ __launch_bounds__(128) void k1_kernel(
        const float* __restrict__ logits1,   // (1600,25,1)
        const float* __restrict__ tlogits,   // (1600,25,97)
        const float* __restrict__ cen,       // (96,300)
        const float* __restrict__ tgt_pts,   // (512,50)
        float* __restrict__ gram, float* __restrict__ logp,
        float* __restrict__ cost_class, float* __restrict__ tgtT) {
    __shared__ float smem[448];              // gram: row[0..300)+red[320..448); pred: pA[2][97]
    int blk = blockIdx.x, tid = threadIdx.x;
    int wave = tid >> 6, lane = tid & 63;

    if (blk < GRAM_BLKS) {
        float* row = smem;                   // 300
        float* red = smem + 320;             // 128
        for (int k = tid; k < EDIM; k += 128) row[k] = cen[blk * EDIM + k];
        if (blk == 0 && tid < VOC) gram[VOC * VOC + tid] = 0.f;   // zero pad row
        __syncthreads();
        float e = 0.f;
        if (tid < VOC) {
            float a0 = 0.f, a1 = 0.f;
            const float* c = cen + (size_t)tid * EDIM;
            for (int k = 0; k < EDIM; k += 2) { a0 += row[k] * c[k]; a1 += row[k + 1] * c[k + 1]; }
            e = __expf((a0 + a1) * 0.05773502691896258f);
        }
        red[tid] = e;
        __syncthreads();
        for (int s = 64; s; s >>= 1) { if (tid < s) red[tid] += red[tid + s]; __syncthreads(); }
        if (tid < VOC) gram[blk * VOC + tid] = e / red[0];
    } else if (blk < GRAM_BLKS + PRED_BLKS) {
        int u = blk - GRAM_BLKS;
        const float* base = tlogits + (size_t)u * NPTS * NC;
        float e0[13], e1[13], s[13], vm[13];
        int p0 = wave * 13;                  // wave0: 13 pts, wave1: 12 pts
#pragma unroll
        for (int i = 0; i < 13; ++i) {
            int p = p0 + i;
            bool ok = p < NPTS;
            vm[i] = ok ? 1.f : 0.f;
            int pe = ok ? p : 0;
            float x0 = base[pe * NC + lane];
            float x1 = (lane < 33) ? base[pe * NC + 64 + lane] : 0.f;
            e0[i] = __expf(x0);
            e1[i] = (lane < 33) ? __expf(x1) : 0.f;
            s[i] = e0[i] + e1[i];
        }
#pragma unroll
        for (int st = 32; st; st >>= 1) {
#pragma unroll
            for (int i = 0; i < 13; ++i) s[i] += __shfl_xor(s[i], st);
        }
        float part0 = 0.f, part1 = 0.f;
#pragma unroll
        for (int i = 0; i < 13; ++i) {
            float rinv = vm[i] / s[i];
            part0 += e0[i] * rinv;
            part1 += e1[i] * rinv;
        }
        float* pA = smem;                    // [2][97]
        pA[wave * 97 + lane] = part0;
        if (lane < 33) pA[wave * 97 + 64 + lane] = part1;
        __syncthreads();
        if (tid < VOC) {
            float tot = (pA[tid] + pA[97 + tid]) * 0.04f;
            logp[(size_t)u * VOC + tid] = __logf(fmaxf(tot, 1e-6f));
        }
        if (wave == 1) {
            float sig = 0.f;
            if (lane < NPTS) { float x = logits1[u * NPTS + lane]; sig = 1.f / (1.f + __expf(-x)); }
#pragma unroll
            for (int o = 32; o; o >>= 1) sig += __shfl_xor(sig, o);
            if (lane == 0) {
                float prob = sig * 0.04f;
                float negc = 0.75f * prob * prob * (-__logf(1.f - prob + 1e-8f));
                float posc = 0.25f * (1.f - prob) * (1.f - prob) * (-__logf(prob + 1e-8f));
                cost_class[u] = posc - negc;
            }
        }
    } else {
        int g = (blk - GRAM_BLKS - PRED_BLKS) * 128 + tid;   // < 25600 exactly
        int k = g / NCOL;
        int j = g - k * NCOL;
        tgtT[g] = tgt_pts[(size_t)j * NDIM + k];
    }
}

// ================= K2a: tgt-stats, 128 blocks x 256, 1 pair per wave =================
__global__ __launch_bounds__(256) void stats_kernel(
        const int*   __restrict__ texts,     // (512,25)
        const float* __restrict__ gram,      // (97,96), row 96 zeros
        float* __restrict__ stat) {          // (512,97)
    __shared__ int s_tex[4 * MAXLEN];
    int blk = blockIdx.x, tid = threadIdx.x;
    int wave = tid >> 6, lane = tid & 63;
    if (tid < 4 * MAXLEN) s_tex[tid] = texts[blk * 4 * MAXLEN + tid];
    __syncthreads();

    int vv[MAXLEN];
#pragma unroll
    for (int l = 0; l < MAXLEN; ++l) vv[l] = s_tex[wave * MAXLEN + l];
    int len = 0;
#pragma unroll
    for (int l = 0; l < MAXLEN; ++l) len += (vv[l] != VOC);
    float a0 = 0.f, a1 = 0.f;
#pragma unroll
    for (int l0 = 0; l0 < MAXLEN; l0 += 5) {
        float b0[5], b1[5];
#pragma unroll
        for (int q = 0; q < 5; ++q) {                 // 10 loads in flight
            const float* gr = gram + vv[l0 + q] * VOC;   // row 96 = zeros
            b0[q] = gr[lane];
            b1[q] = (lane < 32) ? gr[64 + lane] : 0.f;
        }
#pragma unroll
        for (int q = 0; q < 5; ++q) { a0 += b0[q]; a1 += b1[q]; }
    }
    float dinv = 1.f / (float)(len > 0 ? len : 1);
    float t0 = fmaxf(a0 * dinv, 1e-6f);
    float t1 = (lane < 32) ? fmaxf(a1 * dinv, 1e-6f) : 0.f;
    float s = t0 + t1;
#pragma unroll
    for (int o = 32; o; o >>= 1) s += __shfl_xor(s, o);
    float inv = 1.f / s;
    float ts0 = t0 * inv, ts1 = t1 * inv;
    float c0 = ts0 * __logf(ts0);
    float c1 = (lane < 32) ? ts1 * __logf(ts1) : 0.f;
    float ent = c0 + c1;
#pragma unroll
    for (int o = 32; o; o >>= 1) ent += __shfl_xor(ent, o);
    float* dst = stat + (size_t)(blk * 4 + wave) * NC;
    dst[lane] = len ? ts0 : 0.f;
    if (lane < 32) dst[64 + lane] = len ? ts1 : 0.f;
    if (lane == 0) dst[VOC] = len ? ent : 100.f;
}

// ================= K2b: pure assemble, 1600 blocks x 256 = (row-pair, col-half) =================
__global__ __launch_bounds__(256) void asm_kernel(
        const float* __restrict__ pred_pts,  // (1600,50)
        const float* __restrict__ tgtT,      // (50,512)
        const float* __restrict__ logp,      // (1600,96)
        const float* __restrict__ cc,        // (1600,)
        const float* __restrict__ stat,      // (512,97)
        float* __restrict__ out) {           // (1600,512)
    __shared__ float s_lp[2][VOC];
    __shared__ float s_pp[2][NDIM];
    __shared__ float s_ct[2][NGT];
    __shared__ float spart[256];
    __shared__ float s_cc[2];

    int blk = blockIdx.x, tid = threadIdx.x;
    int pairIdx = blk >> 1, half = blk & 1;
    int r0 = pairIdx * 2;
    int b = pairIdx / 50;                    // rows 2k,2k+1 share image b = r0/100
    int col0 = half << 8;                    // 0 or 256
    bool hasText = ((b >> 3) == half);       // image b's 32 cols live in this half?

    // ---- stage (tiny, coalesced)
    if (tid < 2 * NDIM) { int r = tid >= NDIM, k = tid - r * NDIM; s_pp[r][k] = pred_pts[(size_t)(r0 + r) * NDIM + k]; }
    if (tid < 2) s_cc[tid] = cc[r0 + tid];
    if (hasText && tid >= 64 && tid < 64 + 2 * VOC) {
        int t = tid - 64;
        int r = t >= VOC, c = t - r * VOC;
        s_lp[r][c] = logp[(size_t)(r0 + r) * VOC + c];
    }
    __syncthreads();

    // ---- KL (only in the matching half): 256 thr = 64 (row,g) x 4 sub-chunks of 24
    if (hasText) {
        {
            int pair = tid >> 2, sub = tid & 3;
            int row = pair >> 5, g = pair & 31;
            const float* L = s_lp[row] + sub * 24;
            const float* S = stat + (size_t)(b * NGT + g) * NC + sub * 24;   // L2-resident
            float d0 = 0.f, d1 = 0.f;
#pragma unroll
            for (int j = 0; j < 24; j += 2) { d0 += L[j] * S[j]; d1 += L[j + 1] * S[j + 1]; }
            spart[tid] = d0 + d1;
        }
        __syncthreads();
        if (tid < 2 * NGT) {
            int row = tid >> 5, g = tid & 31;
            float s = spart[tid * 4] + spart[tid * 4 + 1] + spart[tid * 4 + 2] + spart[tid * 4 + 3];
            s_ct[row][g] = fmaxf(stat[(size_t)(b * NGT + g) * NC + VOC] - s, 0.f);
        }
    }

    // ---- L1 sweep: 2 rows x 1 col/thread over this half
    float a0 = 0.f, a1 = 0.f;
#pragma unroll 10
    for (int k = 0; k < NDIM; ++k) {
        float tv = tgtT[(k << 9) + col0 + tid];
        a0 += fabsf(s_pp[0][k] - tv);
        a1 += fabsf(s_pp[1][k] - tv);
    }
    __syncthreads();                         // s_ct visible

    int gb = tid >> 5, g = tid & 31;
    float m = (hasText && gb == (b & 7)) ? 1.f : 0.f;
    float c0v = s_cc[0], c1v = s_cc[1];
    float t0 = m * (hasText ? s_ct[0][g] : 0.f);
    float t1 = m * (hasText ? s_ct[1][g] : 0.f);
    out[(size_t)r0 * NCOL + col0 + tid]       = c0v + a0 + t0;
    out[(size_t)(r0 + 1) * NCOL + col0 + tid] = c1v + a1 + t1;
}

extern "C" void kernel_launch(void* const* d_in, const int* in_sizes, int n_in,
                              void* d_out, int out_size, void* d_ws, size_t ws_size,
                              hipStream_t stream) {
    const float* pred_logits      = (const float*)d_in[0];
    const float* pred_ctrl_points = (const float*)d_in[1];
    const float* pred_text_logits = (const float*)d_in[2];
    const float* tgt_ctrl_points  = (const float*)d_in[3];
    const int*   target_texts     = (const int*)d_in[4];
    const float* centroids        = (const float*)d_in[5];
    float* out = (float*)d_out;
    float* ws  = (float*)d_ws;

    float* gram = ws + WS_GRAM;
    float* logp = ws + WS_LOGP;
    float* cc   = ws + WS_CC;
    float* tgtT = ws + WS_TGTT;
    float* stat = ws + WS_STAT;

    k1_kernel<<<K1_BLKS, 128, 0, stream>>>(pred_logits, pred_text_logits, centroids,
                                           tgt_ctrl_points, gram, logp, cc, tgtT);
    stats_kernel<<<128, 256, 0, stream>>>(target_texts, gram, stat);
    asm_kernel<<<1600, 256, 0, stream>>>(pred_ctrl_points, tgtT, logp, cc, stat, out);
}